// Round 2
// baseline (3620.948 us; speedup 1.0000x reference)
//
#include <hip/hip_runtime.h>

typedef unsigned short ushort_t;
typedef unsigned int   uint_t;

#define NTOK 50176          // B*D*Hp*Wp = 2*8*56*56
#define NWIN 98             // (8/4)*(56/8)*(56/8)
#define NBIAS 1575          // 7*15*15

typedef __attribute__((ext_vector_type(8))) short bf16x8;
typedef __attribute__((ext_vector_type(4))) float floatx4;

static __device__ __forceinline__ float lo2f(uint_t u) { return __uint_as_float(u << 16); }
static __device__ __forceinline__ float hi2f(uint_t u) { return __uint_as_float(u & 0xffff0000u); }
static __device__ __forceinline__ ushort_t f2b(float f) {
    union { float f; uint_t u; } v; v.f = f;
    uint_t u = v.u + 0x7fffu + ((v.u >> 16) & 1u);
    return (ushort_t)(u >> 16);
}

// ---------------- weight transpose + fp32->bf16 cast: dst[n*K+k] = bf16(src[k*N+n])
__global__ void transpose_w(const float* __restrict__ src, ushort_t* __restrict__ dst,
                            int K, int N) {
    long base = (long)blockIdx.y * K * N;
    int idx = blockIdx.x * 256 + threadIdx.x;
    if (idx < K * N) {
        int k = idx / N, n = idx - k * N;
        dst[base + (long)n * K + k] = f2b(src[base + idx]);
    }
}

// ---------------- patch-merge conv (fp32 in, fp32 out): one block per token, 256 out ch
__global__ void conv_kernel(const float* __restrict__ X, const float* __restrict__ CW,
                            const float* __restrict__ CB, float* __restrict__ Y) {
    __shared__ float xs[64];
    int t = blockIdx.x;
    int w = t % 56, h = (t / 56) % 56, d = (t / 3136) % 8, b = t / 25088;
    int tid = threadIdx.x;
    if (tid < 64) {
        int ic = tid >> 4, kh = (tid >> 2) & 3, kw = tid & 3;
        long xi = (((long)(b * 4 + ic) * 8 + d) * 224 + (h * 4 + kh)) * 224 + (w * 4 + kw);
        xs[tid] = X[xi];
    }
    __syncthreads();
    int c = tid;
    float acc = CB[c];
    const float4* wp4 = (const float4*)(CW + c * 64);
#pragma unroll
    for (int p = 0; p < 16; ++p) {
        float4 u = wp4[p];
        acc += xs[p*4+0] * u.x + xs[p*4+1] * u.y + xs[p*4+2] * u.z + xs[p*4+3] * u.w;
    }
    Y[(long)t * 256 + c] = acc;
}

// ---------------- LayerNorm: 4 tokens per block, one wave per token; fp32 in, bf16 out
__global__ void ln_kernel(const float* __restrict__ Y, ushort_t* __restrict__ Xn,
                          const float* __restrict__ S, const float* __restrict__ Bb) {
    int wv = threadIdx.x >> 6, lane = threadIdx.x & 63;
    long t = (long)blockIdx.x * 4 + wv;
    const float* y = Y + t * 256;
    float v[4], s = 0.f, s2 = 0.f;
#pragma unroll
    for (int r = 0; r < 4; ++r) { v[r] = y[lane + 64 * r]; s += v[r]; s2 += v[r] * v[r]; }
#pragma unroll
    for (int off = 32; off; off >>= 1) { s += __shfl_xor(s, off, 64); s2 += __shfl_xor(s2, off, 64); }
    float mu = s * (1.f / 256.f);
    float var = s2 * (1.f / 256.f) - mu * mu;
    float rstd = rsqrtf(var + 1e-5f);
#pragma unroll
    for (int r = 0; r < 4; ++r) {
        int c = lane + 64 * r;
        Xn[t * 256 + c] = f2b((v[r] - mu) * rstd * S[c] + Bb[c]);
    }
}

// ---------------- GEMM: C[M,N] = A[M,K] @ B[K,N] via BT[N,K]; m97-style 128x128 tile
// mode 0: store bf16; mode 1: bias+gelu, store bf16; mode 2: bias, Y += (fp32)
__global__ __launch_bounds__(256, 2) void gemm_bt(
    const ushort_t* __restrict__ A, const ushort_t* __restrict__ BT,
    int M, int N, int K,
    const float* __restrict__ bias, int mode,
    ushort_t* __restrict__ C, float* __restrict__ Y) {
    __shared__ ushort_t As[128 * 32];
    __shared__ ushort_t Bs[128 * 32];
    const int tid = threadIdx.x;
    const int wv = tid >> 6;
    const int lane = tid & 63;
    const int quad = lane >> 4;
    const int l15 = lane & 15;
    const long m0 = (long)blockIdx.x * 128;
    const long n0 = (long)blockIdx.y * 128;
    const int wm = (wv & 1) * 64;
    const int wn = (wv >> 1) * 64;
    const int r_loc = lane >> 2;        // 0..15
    const int k_loc = (lane & 3) * 8;   // 0,8,16,24

    floatx4 acc[4][4] = {};

    const ushort_t* Ab = A + m0 * K;
    const ushort_t* Bb = BT + n0 * K;

    for (int kt = 0; kt < K; kt += 32) {
#pragma unroll
        for (int q = 0; q < 2; ++q) {
            int slot = wv * 2 + q;
            int row = slot * 16 + r_loc;
            __builtin_amdgcn_global_load_lds(
                (const __attribute__((address_space(1))) void*)(Ab + (long)row * K + kt + k_loc),
                (__attribute__((address_space(3))) void*)(As + slot * 512), 16, 0, 0);
            __builtin_amdgcn_global_load_lds(
                (const __attribute__((address_space(1))) void*)(Bb + (long)row * K + kt + k_loc),
                (__attribute__((address_space(3))) void*)(Bs + slot * 512), 16, 0, 0);
        }
        __syncthreads();
        bf16x8 af[4], bfr[4];
#pragma unroll
        for (int i = 0; i < 4; ++i) {
            af[i]  = *(const bf16x8*)(As + (wm + i * 16 + l15) * 32 + quad * 8);
            bfr[i] = *(const bf16x8*)(Bs + (wn + i * 16 + l15) * 32 + quad * 8);
        }
#pragma unroll
        for (int mi = 0; mi < 4; ++mi)
#pragma unroll
            for (int ni = 0; ni < 4; ++ni)
                acc[mi][ni] = __builtin_amdgcn_mfma_f32_16x16x32_bf16(af[mi], bfr[ni], acc[mi][ni], 0, 0, 0);
        __syncthreads();
    }

    if (mode == 2) {
#pragma unroll
        for (int mi = 0; mi < 4; ++mi)
#pragma unroll
            for (int ni = 0; ni < 4; ++ni) {
                long col = n0 + wn + ni * 16 + l15;
                float bv = bias[col];
#pragma unroll
                for (int r = 0; r < 4; ++r) {
                    long row = m0 + wm + mi * 16 + quad * 4 + r;
                    Y[row * N + col] += acc[mi][ni][r] + bv;
                }
            }
    } else {
#pragma unroll
        for (int mi = 0; mi < 4; ++mi)
#pragma unroll
            for (int ni = 0; ni < 4; ++ni) {
                long col = n0 + wn + ni * 16 + l15;
                float bv = bias ? bias[col] : 0.f;
#pragma unroll
                for (int r = 0; r < 4; ++r) {
                    long row = m0 + wm + mi * 16 + quad * 4 + r;
                    float v = acc[mi][ni][r] + bv;
                    if (mode == 1) {
                        float x3 = v * v * v;
                        v = 0.5f * v * (1.f + tanhf(0.7978845608028654f * (v + 0.044715f * x3)));
                    }
                    C[row * N + col] = f2b(v);
                }
            }
    }
}

// ---------------- window attention: one block per (window, head, batch); thread = query pos
__global__ __launch_bounds__(256, 2) void attn_kernel(
    const ushort_t* __restrict__ QKV, ushort_t* __restrict__ O,
    const float* __restrict__ BiasTab, int shifted) {
    __shared__ uint_t ks[256 * 16];   // packed bf16 pairs
    __shared__ uint_t vs[256 * 16];
    __shared__ float bias_s[NBIAS];
    __shared__ int reg_s[256];
    const int i = threadIdx.x;
    const int wdx = blockIdx.x, hd = blockIdx.y, b = blockIdx.z;
    const int wd = wdx / 49;
    const int wh = (wdx / 7) % 7;
    const int ww = wdx % 7;
    const int di = i >> 6, hi = (i >> 3) & 7, wi = i & 7;
    const int d = wd * 4 + di, h = wh * 8 + hi, w = ww * 8 + wi;
    int d0 = d, h0 = h, w0 = w;
    if (shifted) { d0 = (d + 2) & 7; h0 = (h + 4) % 56; w0 = (w + 4) % 56; }
    const long tok = ((long)((b * 8 + d0) * 56 + h0)) * 56 + w0;
    if (shifted) {
        int rd = d < 4 ? 0 : (d < 6 ? 1 : 2);
        int rh = h < 48 ? 0 : (h < 52 ? 1 : 2);
        int rw = w < 48 ? 0 : (w < 52 ? 1 : 2);
        reg_s[i] = rd * 9 + rh * 3 + rw;
    } else reg_s[i] = 0;
    {
        const uint4* kp = (const uint4*)(QKV + tok * 768 + 256 + hd * 32);
        const uint4* vp = (const uint4*)(QKV + tok * 768 + 512 + hd * 32);
#pragma unroll
        for (int p = 0; p < 4; ++p) {
            uint4 kv = kp[p], vv = vp[p];
            ks[i * 16 + p * 4 + 0] = kv.x; ks[i * 16 + p * 4 + 1] = kv.y;
            ks[i * 16 + p * 4 + 2] = kv.z; ks[i * 16 + p * 4 + 3] = kv.w;
            vs[i * 16 + p * 4 + 0] = vv.x; vs[i * 16 + p * 4 + 1] = vv.y;
            vs[i * 16 + p * 4 + 2] = vv.z; vs[i * 16 + p * 4 + 3] = vv.w;
        }
    }
    for (int r = i; r < NBIAS; r += 256) bias_s[r] = BiasTab[r * 8 + hd];
    float q[32];
    {
        const uint4* qp = (const uint4*)(QKV + tok * 768 + hd * 32);
#pragma unroll
        for (int p = 0; p < 4; ++p) {
            uint4 u = qp[p];
            q[p*8+0] = lo2f(u.x); q[p*8+1] = hi2f(u.x);
            q[p*8+2] = lo2f(u.y); q[p*8+3] = hi2f(u.y);
            q[p*8+4] = lo2f(u.z); q[p*8+5] = hi2f(u.z);
            q[p*8+6] = lo2f(u.w); q[p*8+7] = hi2f(u.w);
        }
#pragma unroll
        for (int dd = 0; dd < 32; ++dd) q[dd] *= 0.17677669529663687f;
    }
    __syncthreads();
    const int myreg = reg_s[i];
    float m = -3e38f, l = 0.f, o[32];
#pragma unroll
    for (int dd = 0; dd < 32; ++dd) o[dd] = 0.f;
    for (int j = 0; j < 256; ++j) {
        const uint_t* kr = ks + j * 16;
        float s = 0.f;
#pragma unroll
        for (int p = 0; p < 16; ++p) {
            uint_t u = kr[p];
            s += q[2*p] * lo2f(u) + q[2*p+1] * hi2f(u);
        }
        int dj = j >> 6, hj = (j >> 3) & 7, wj = j & 7;
        s += bias_s[(di - dj + 3) * 225 + (hi - hj + 7) * 15 + (wi - wj + 7)];
        if (shifted && (reg_s[j] != myreg)) s -= 1e9f;
        if (s > m) {
            float corr = __expf(m - s);
            l *= corr;
#pragma unroll
            for (int dd = 0; dd < 32; ++dd) o[dd] *= corr;
            m = s;
        }
        float p = __expf(s - m);
        l += p;
        const uint_t* vr = vs + j * 16;
#pragma unroll
        for (int pp = 0; pp < 16; ++pp) {
            uint_t u = vr[pp];
            o[2*pp]   += p * lo2f(u);
            o[2*pp+1] += p * hi2f(u);
        }
    }
    float inv = 1.f / l;
    uint4* op4 = (uint4*)(O + tok * 256 + hd * 32);
#pragma unroll
    for (int p = 0; p < 4; ++p) {
        uint4 u;
        u.x = (uint_t)f2b(o[p*8+0] * inv) | ((uint_t)f2b(o[p*8+1] * inv) << 16);
        u.y = (uint_t)f2b(o[p*8+2] * inv) | ((uint_t)f2b(o[p*8+3] * inv) << 16);
        u.z = (uint_t)f2b(o[p*8+4] * inv) | ((uint_t)f2b(o[p*8+5] * inv) << 16);
        u.w = (uint_t)f2b(o[p*8+6] * inv) | ((uint_t)f2b(o[p*8+7] * inv) << 16);
        op4[p] = u;
    }
}

// ---------------- final permute: y (tok, C) fp32 -> out (B, C, D, Hp, Wp) fp32
__global__ void out_permute(const float* __restrict__ Y, float* __restrict__ Out) {
    __shared__ float tile[64][65];
    const int t0 = blockIdx.x * 64;
    const int c0 = blockIdx.y * 64;
    const int tid = threadIdx.x;
    const int a = tid >> 6;
    const int bx = tid & 63;
#pragma unroll
    for (int s8 = 0; s8 < 16; ++s8) {
        int tt = a + s8 * 4;
        tile[tt][bx] = Y[(long)(t0 + tt) * 256 + c0 + bx];
    }
    __syncthreads();
#pragma unroll
    for (int s8 = 0; s8 < 16; ++s8) {
        int cc = a + s8 * 4;
        int tok = t0 + bx;
        int bb = tok / 25088;
        int rem = tok - bb * 25088;
        Out[((long)(bb * 256 + c0 + cc)) * 25088 + rem] = tile[bx][cc];
    }
}

extern "C" void kernel_launch(void* const* d_in, const int* in_sizes, int n_in,
                              void* d_out, int out_size, void* d_ws, size_t ws_size,
                              hipStream_t stream) {
    (void)in_sizes; (void)n_in; (void)out_size; (void)ws_size;
    const float* x        = (const float*)d_in[0];
    const float* conv_w   = (const float*)d_in[1];
    const float* conv_b   = (const float*)d_in[2];
    const float* ln1_s    = (const float*)d_in[3];
    const float* ln1_b    = (const float*)d_in[4];
    const float* qkv_w    = (const float*)d_in[5];
    const float* out_w    = (const float*)d_in[6];
    const float* out_b    = (const float*)d_in[7];
    const float* bias_tab = (const float*)d_in[8];
    const float* ln2_s    = (const float*)d_in[9];
    const float* ln2_b    = (const float*)d_in[10];
    const float* fc1_w    = (const float*)d_in[11];
    const float* fc1_b    = (const float*)d_in[12];
    const float* fc2_w    = (const float*)d_in[13];
    const float* fc2_b    = (const float*)d_in[14];
    float* out = (float*)d_out;

    char* ws = (char*)d_ws;
    float*    y    = (float*)ws;    ws += (size_t)NTOK * 256 * 4;   // fp32 residual stream
    ushort_t* big  = (ushort_t*)ws; ws += (size_t)NTOK * 1024 * 2;  // qkv (768) / h1 (1024) bf16
    ushort_t* xob  = (ushort_t*)ws; ws += (size_t)NTOK * 256 * 2;   // LN out / attn out bf16
    ushort_t* bt_qkv = (ushort_t*)ws; ws += (size_t)4 * 768 * 256 * 2;
    ushort_t* bt_out = (ushort_t*)ws; ws += (size_t)4 * 256 * 256 * 2;
    ushort_t* bt_fc1 = (ushort_t*)ws; ws += (size_t)4 * 1024 * 256 * 2;
    ushort_t* bt_fc2 = (ushort_t*)ws; ws += (size_t)4 * 256 * 1024 * 2;

    transpose_w<<<dim3((256 * 768 + 255) / 256, 4), 256, 0, stream>>>(qkv_w, bt_qkv, 256, 768);
    transpose_w<<<dim3((256 * 256 + 255) / 256, 4), 256, 0, stream>>>(out_w, bt_out, 256, 256);
    transpose_w<<<dim3((256 * 1024 + 255) / 256, 4), 256, 0, stream>>>(fc1_w, bt_fc1, 256, 1024);
    transpose_w<<<dim3((1024 * 256 + 255) / 256, 4), 256, 0, stream>>>(fc2_w, bt_fc2, 1024, 256);

    conv_kernel<<<NTOK, 256, 0, stream>>>(x, conv_w, conv_b, y);

    for (int i = 0; i < 4; ++i) {
        int sh = i & 1;
        // LN1 -> xob (bf16)
        ln_kernel<<<NTOK / 4, 256, 0, stream>>>(y, xob, ln1_s + i * 256, ln1_b + i * 256);
        // QKV = xob @ qkv_w -> big [tok,768]
        gemm_bt<<<dim3(NTOK / 128, 6), 256, 0, stream>>>(
            xob, bt_qkv + (size_t)i * 768 * 256, NTOK, 768, 256, nullptr, 0, big, nullptr);
        // window attention -> xob [tok,256]
        attn_kernel<<<dim3(NWIN, 8, 2), 256, 0, stream>>>(
            big, xob, bias_tab + (size_t)i * NBIAS * 8, sh);
        // y += xob @ out_w + out_b
        gemm_bt<<<dim3(NTOK / 128, 2), 256, 0, stream>>>(
            xob, bt_out + (size_t)i * 256 * 256, NTOK, 256, 256, out_b + i * 256, 2, nullptr, y);
        // LN2 -> xob
        ln_kernel<<<NTOK / 4, 256, 0, stream>>>(y, xob, ln2_s + i * 256, ln2_b + i * 256);
        // h1 = gelu(xob @ fc1_w + fc1_b) -> big [tok,1024]
        gemm_bt<<<dim3(NTOK / 128, 8), 256, 0, stream>>>(
            xob, bt_fc1 + (size_t)i * 1024 * 256, NTOK, 1024, 256, fc1_b + i * 1024, 1, big, nullptr);
        // y += big @ fc2_w + fc2_b
        gemm_bt<<<dim3(NTOK / 128, 2), 256, 0, stream>>>(
            big, bt_fc2 + (size_t)i * 256 * 1024, NTOK, 256, 1024, fc2_b + i * 256, 2, nullptr, y);
    }

    out_permute<<<dim3(NTOK / 64, 4), 256, 0, stream>>>(y, out);
}

// Round 3
// 1847.415 us; speedup vs baseline: 1.9600x; 1.9600x over previous
//
#include <hip/hip_runtime.h>

typedef unsigned short ushort_t;
typedef unsigned int   uint_t;

#define NTOK 50176          // B*D*Hp*Wp = 2*8*56*56
#define NWIN 98             // (8/4)*(56/8)*(56/8)
#define NBIAS 1575          // 7*15*15

typedef __attribute__((ext_vector_type(8))) short bf16x8;
typedef __attribute__((ext_vector_type(4))) float floatx4;

static __device__ __forceinline__ float lo2f(uint_t u) { return __uint_as_float(u << 16); }
static __device__ __forceinline__ float hi2f(uint_t u) { return __uint_as_float(u & 0xffff0000u); }
static __device__ __forceinline__ ushort_t f2b(float f) {
    union { float f; uint_t u; } v; v.f = f;
    uint_t u = v.u + 0x7fffu + ((v.u >> 16) & 1u);
    return (ushort_t)(u >> 16);
}

// ---------------- weight transpose + fp32->bf16 cast: dst[n*K+k] = bf16(src[k*N+n])
__global__ void transpose_w(const float* __restrict__ src, ushort_t* __restrict__ dst,
                            int K, int N) {
    long base = (long)blockIdx.y * K * N;
    int idx = blockIdx.x * 256 + threadIdx.x;
    if (idx < K * N) {
        int k = idx / N, n = idx - k * N;
        dst[base + (long)n * K + k] = f2b(src[base + idx]);
    }
}

// ---------------- patch-merge conv (fp32 in, fp32 out)
__global__ void conv_kernel(const float* __restrict__ X, const float* __restrict__ CW,
                            const float* __restrict__ CB, float* __restrict__ Y) {
    __shared__ float xs[64];
    int t = blockIdx.x;
    int w = t % 56, h = (t / 56) % 56, d = (t / 3136) % 8, b = t / 25088;
    int tid = threadIdx.x;
    if (tid < 64) {
        int ic = tid >> 4, kh = (tid >> 2) & 3, kw = tid & 3;
        long xi = (((long)(b * 4 + ic) * 8 + d) * 224 + (h * 4 + kh)) * 224 + (w * 4 + kw);
        xs[tid] = X[xi];
    }
    __syncthreads();
    int c = tid;
    float acc = CB[c];
    const float4* wp4 = (const float4*)(CW + c * 64);
#pragma unroll
    for (int p = 0; p < 16; ++p) {
        float4 u = wp4[p];
        acc += xs[p*4+0] * u.x + xs[p*4+1] * u.y + xs[p*4+2] * u.z + xs[p*4+3] * u.w;
    }
    Y[(long)t * 256 + c] = acc;
}

// ---------------- LayerNorm: 4 tokens per block, one wave per token; fp32 in, bf16 out
__global__ void ln_kernel(const float* __restrict__ Y, ushort_t* __restrict__ Xn,
                          const float* __restrict__ S, const float* __restrict__ Bb) {
    int wv = threadIdx.x >> 6, lane = threadIdx.x & 63;
    long t = (long)blockIdx.x * 4 + wv;
    const float* y = Y + t * 256;
    float v[4], s = 0.f, s2 = 0.f;
#pragma unroll
    for (int r = 0; r < 4; ++r) { v[r] = y[lane + 64 * r]; s += v[r]; s2 += v[r] * v[r]; }
#pragma unroll
    for (int off = 32; off; off >>= 1) { s += __shfl_xor(s, off, 64); s2 += __shfl_xor(s2, off, 64); }
    float mu = s * (1.f / 256.f);
    float var = s2 * (1.f / 256.f) - mu * mu;
    float rstd = rsqrtf(var + 1e-5f);
#pragma unroll
    for (int r = 0; r < 4; ++r) {
        int c = lane + 64 * r;
        Xn[t * 256 + c] = f2b((v[r] - mu) * rstd * S[c] + Bb[c]);
    }
}

// ---------------- GEMM: C[M,N] = A[M,K] @ B[K,N] via BT[N,K]; m97-style 128x128 tile
__global__ __launch_bounds__(256, 2) void gemm_bt(
    const ushort_t* __restrict__ A, const ushort_t* __restrict__ BT,
    int M, int N, int K,
    const float* __restrict__ bias, int mode,
    ushort_t* __restrict__ C, float* __restrict__ Y) {
    __shared__ ushort_t As[128 * 32];
    __shared__ ushort_t Bs[128 * 32];
    const int tid = threadIdx.x;
    const int wv = tid >> 6;
    const int lane = tid & 63;
    const int quad = lane >> 4;
    const int l15 = lane & 15;
    const long m0 = (long)blockIdx.x * 128;
    const long n0 = (long)blockIdx.y * 128;
    const int wm = (wv & 1) * 64;
    const int wn = (wv >> 1) * 64;
    const int r_loc = lane >> 2;
    const int k_loc = (lane & 3) * 8;

    floatx4 acc[4][4] = {};

    const ushort_t* Ab = A + m0 * K;
    const ushort_t* Bb = BT + n0 * K;

    for (int kt = 0; kt < K; kt += 32) {
#pragma unroll
        for (int q = 0; q < 2; ++q) {
            int slot = wv * 2 + q;
            int row = slot * 16 + r_loc;
            __builtin_amdgcn_global_load_lds(
                (const __attribute__((address_space(1))) void*)(Ab + (long)row * K + kt + k_loc),
                (__attribute__((address_space(3))) void*)(As + slot * 512), 16, 0, 0);
            __builtin_amdgcn_global_load_lds(
                (const __attribute__((address_space(1))) void*)(Bb + (long)row * K + kt + k_loc),
                (__attribute__((address_space(3))) void*)(Bs + slot * 512), 16, 0, 0);
        }
        __syncthreads();
        bf16x8 af[4], bfr[4];
#pragma unroll
        for (int i = 0; i < 4; ++i) {
            af[i]  = *(const bf16x8*)(As + (wm + i * 16 + l15) * 32 + quad * 8);
            bfr[i] = *(const bf16x8*)(Bs + (wn + i * 16 + l15) * 32 + quad * 8);
        }
#pragma unroll
        for (int mi = 0; mi < 4; ++mi)
#pragma unroll
            for (int ni = 0; ni < 4; ++ni)
                acc[mi][ni] = __builtin_amdgcn_mfma_f32_16x16x32_bf16(af[mi], bfr[ni], acc[mi][ni], 0, 0, 0);
        __syncthreads();
    }

    if (mode == 2) {
#pragma unroll
        for (int mi = 0; mi < 4; ++mi)
#pragma unroll
            for (int ni = 0; ni < 4; ++ni) {
                long col = n0 + wn + ni * 16 + l15;
                float bv = bias[col];
#pragma unroll
                for (int r = 0; r < 4; ++r) {
                    long row = m0 + wm + mi * 16 + quad * 4 + r;
                    Y[row * N + col] += acc[mi][ni][r] + bv;
                }
            }
    } else {
#pragma unroll
        for (int mi = 0; mi < 4; ++mi)
#pragma unroll
            for (int ni = 0; ni < 4; ++ni) {
                long col = n0 + wn + ni * 16 + l15;
                float bv = bias ? bias[col] : 0.f;
#pragma unroll
                for (int r = 0; r < 4; ++r) {
                    long row = m0 + wm + mi * 16 + quad * 4 + r;
                    float v = acc[mi][ni][r] + bv;
                    if (mode == 1) {
                        float x3 = v * v * v;
                        v = 0.5f * v * (1.f + tanhf(0.7978845608028654f * (v + 0.044715f * x3)));
                    }
                    C[row * N + col] = f2b(v);
                }
            }
    }
}

// ---------------- MFMA window attention: block = (window, head, batch), 4 waves
// Each wave, per row-group rg, computes 16 query rows x 256 keys via MFMA,
// full-row softmax in C-layout regs, P -> LDS (bf16) -> A-frags, PV via MFMA.
#define PSTRIDE 260
#define VTSTRIDE 264
__global__ __launch_bounds__(256, 2) void attn_mfma(
    const ushort_t* __restrict__ QKV, ushort_t* __restrict__ O,
    const float* __restrict__ BiasTab, int shifted) {
    __shared__ ushort_t Ks[256 * 32];                 // K rows [tok][dim]
    __shared__ ushort_t Vt[32 * VTSTRIDE];            // V^T [dim][tok]
    __shared__ ushort_t Pl[4 * 16 * PSTRIDE];         // per-wave P tiles
    __shared__ float bias_s[NBIAS];
    __shared__ int tok_s[256];
    __shared__ int reg_s[256];

    const int tid = threadIdx.x;
    const int wv = tid >> 6;
    const int lane = tid & 63;
    const int quad = lane >> 4;
    const int l15 = lane & 15;
    const int wdx = blockIdx.x, hd = blockIdx.y, b = blockIdx.z;
    const int wd = wdx / 49;
    const int wh = (wdx / 7) % 7;
    const int ww = wdx % 7;

    // ---- stage K, V^T, tok, reg, bias
    {
        const int t = tid;
        const int di = t >> 6, hi = (t >> 3) & 7, wi = t & 7;
        const int d = wd * 4 + di, h = wh * 8 + hi, w = ww * 8 + wi;
        int d0 = d, h0 = h, w0 = w;
        if (shifted) { d0 = (d + 2) & 7; h0 = (h + 4) % 56; w0 = (w + 4) % 56; }
        const long tok = ((long)((b * 8 + d0) * 56 + h0)) * 56 + w0;
        tok_s[t] = (int)tok;
        if (shifted) {
            int rd = d < 4 ? 0 : (d < 6 ? 1 : 2);
            int rh = h < 48 ? 0 : (h < 52 ? 1 : 2);
            int rw = w < 48 ? 0 : (w < 52 ? 1 : 2);
            reg_s[t] = rd * 9 + rh * 3 + rw;
        } else reg_s[t] = 0;
        const uint4* kp = (const uint4*)(QKV + tok * 768 + 256 + hd * 32);
        const uint4* vp = (const uint4*)(QKV + tok * 768 + 512 + hd * 32);
        uint4* kd = (uint4*)(Ks + t * 32);
#pragma unroll
        for (int p = 0; p < 4; ++p) kd[p] = kp[p];
#pragma unroll
        for (int p = 0; p < 4; ++p) {
            uint4 vvu = vp[p];
            uint_t uu[4] = {vvu.x, vvu.y, vvu.z, vvu.w};
#pragma unroll
            for (int e = 0; e < 4; ++e) {
                int dd = p * 8 + e * 2;
                Vt[dd * VTSTRIDE + t]       = (ushort_t)(uu[e] & 0xffffu);
                Vt[(dd + 1) * VTSTRIDE + t] = (ushort_t)(uu[e] >> 16);
            }
        }
        for (int r = t; r < NBIAS; r += 256) bias_s[r] = BiasTab[r * 8 + hd];
    }
    __syncthreads();

    const float scale = 0.17677669529663687f;
    ushort_t* Pw = Pl + wv * 16 * PSTRIDE;

    for (int rg = 0; rg < 4; ++rg) {
        const int rti = wv * 4 + rg;
        // Q a-fragment straight from global: row = l15, k = quad*8..+7
        bf16x8 aq;
        {
            int tq = tok_s[rti * 16 + l15];
            const uint4* qp = (const uint4*)(QKV + (long)tq * 768 + hd * 32 + quad * 8);
            union { uint4 u; bf16x8 v; } cv; cv.u = *qp; aq = cv.v;
        }
        // row metadata for this lane's 4 C-rows
        int idv[4], ihv[4], iwv4[4], rq[4];
#pragma unroll
        for (int r = 0; r < 4; ++r) {
            int i = rti * 16 + quad * 4 + r;
            idv[r] = i >> 6; ihv[r] = (i >> 3) & 7; iwv4[r] = i & 7;
            rq[r] = reg_s[i];
        }
        // S = Q @ K^T
        floatx4 Sc[16];
#pragma unroll
        for (int nt = 0; nt < 16; ++nt) {
            bf16x8 bk = *(const bf16x8*)(Ks + (nt * 16 + l15) * 32 + quad * 8);
            floatx4 z = {};
            Sc[nt] = __builtin_amdgcn_mfma_f32_16x16x32_bf16(aq, bk, z, 0, 0, 0);
        }
        // bias + mask + row max
        float m4[4] = {-3e38f, -3e38f, -3e38f, -3e38f};
#pragma unroll
        for (int nt = 0; nt < 16; ++nt) {
            int j = nt * 16 + l15;
            int jd = j >> 6, jh = (j >> 3) & 7, jw = j & 7;
            int rk = reg_s[j];
#pragma unroll
            for (int r = 0; r < 4; ++r) {
                float s = Sc[nt][r] * scale +
                          bias_s[(idv[r] - jd + 3) * 225 + (ihv[r] - jh + 7) * 15 + (iwv4[r] - jw + 7)];
                if (shifted && (rq[r] != rk)) s = -1e9f;
                Sc[nt][r] = s;
                m4[r] = fmaxf(m4[r], s);
            }
        }
#pragma unroll
        for (int r = 0; r < 4; ++r) {
            m4[r] = fmaxf(m4[r], __shfl_xor(m4[r], 1));
            m4[r] = fmaxf(m4[r], __shfl_xor(m4[r], 2));
            m4[r] = fmaxf(m4[r], __shfl_xor(m4[r], 4));
            m4[r] = fmaxf(m4[r], __shfl_xor(m4[r], 8));
        }
        float l4[4] = {0.f, 0.f, 0.f, 0.f};
#pragma unroll
        for (int nt = 0; nt < 16; ++nt)
#pragma unroll
            for (int r = 0; r < 4; ++r) {
                float p = __expf(Sc[nt][r] - m4[r]);
                l4[r] += p;
                Sc[nt][r] = p;
            }
#pragma unroll
        for (int r = 0; r < 4; ++r) {
            l4[r] += __shfl_xor(l4[r], 1);
            l4[r] += __shfl_xor(l4[r], 2);
            l4[r] += __shfl_xor(l4[r], 4);
            l4[r] += __shfl_xor(l4[r], 8);
        }
        // P -> LDS (bf16)
#pragma unroll
        for (int nt = 0; nt < 16; ++nt)
#pragma unroll
            for (int r = 0; r < 4; ++r)
                Pw[(quad * 4 + r) * PSTRIDE + nt * 16 + l15] = f2b(Sc[nt][r]);
        __builtin_amdgcn_s_waitcnt(0xC07F);       // lgkmcnt(0)
        __builtin_amdgcn_wave_barrier();
        // O = P @ V
        float inv4[4];
#pragma unroll
        for (int r = 0; r < 4; ++r) inv4[r] = 1.f / l4[r];
#pragma unroll
        for (int ct = 0; ct < 2; ++ct) {
            floatx4 oa = {};
#pragma unroll
            for (int kt = 0; kt < 8; ++kt) {
                bf16x8 ap = *(const bf16x8*)(Pw + l15 * PSTRIDE + kt * 32 + quad * 8);
                bf16x8 bv = *(const bf16x8*)(Vt + (ct * 16 + l15) * VTSTRIDE + kt * 32 + quad * 8);
                oa = __builtin_amdgcn_mfma_f32_16x16x32_bf16(ap, bv, oa, 0, 0, 0);
            }
#pragma unroll
            for (int r = 0; r < 4; ++r) {
                int i = rti * 16 + quad * 4 + r;
                long tq = tok_s[i];
                O[tq * 256 + hd * 32 + ct * 16 + l15] = f2b(oa[r] * inv4[r]);
            }
        }
        __builtin_amdgcn_s_waitcnt(0xC07F);
        __builtin_amdgcn_wave_barrier();
    }
}

// ---------------- final permute: y (tok, C) fp32 -> out (B, C, D, Hp, Wp) fp32
__global__ void out_permute(const float* __restrict__ Y, float* __restrict__ Out) {
    __shared__ float tile[64][65];
    const int t0 = blockIdx.x * 64;
    const int c0 = blockIdx.y * 64;
    const int tid = threadIdx.x;
    const int a = tid >> 6;
    const int bx = tid & 63;
#pragma unroll
    for (int s8 = 0; s8 < 16; ++s8) {
        int tt = a + s8 * 4;
        tile[tt][bx] = Y[(long)(t0 + tt) * 256 + c0 + bx];
    }
    __syncthreads();
#pragma unroll
    for (int s8 = 0; s8 < 16; ++s8) {
        int cc = a + s8 * 4;
        int tok = t0 + bx;
        int bb = tok / 25088;
        int rem = tok - bb * 25088;
        Out[((long)(bb * 256 + c0 + cc)) * 25088 + rem] = tile[bx][cc];
    }
}

extern "C" void kernel_launch(void* const* d_in, const int* in_sizes, int n_in,
                              void* d_out, int out_size, void* d_ws, size_t ws_size,
                              hipStream_t stream) {
    (void)in_sizes; (void)n_in; (void)out_size; (void)ws_size;
    const float* x        = (const float*)d_in[0];
    const float* conv_w   = (const float*)d_in[1];
    const float* conv_b   = (const float*)d_in[2];
    const float* ln1_s    = (const float*)d_in[3];
    const float* ln1_b    = (const float*)d_in[4];
    const float* qkv_w    = (const float*)d_in[5];
    const float* out_w    = (const float*)d_in[6];
    const float* out_b    = (const float*)d_in[7];
    const float* bias_tab = (const float*)d_in[8];
    const float* ln2_s    = (const float*)d_in[9];
    const float* ln2_b    = (const float*)d_in[10];
    const float* fc1_w    = (const float*)d_in[11];
    const float* fc1_b    = (const float*)d_in[12];
    const float* fc2_w    = (const float*)d_in[13];
    const float* fc2_b    = (const float*)d_in[14];
    float* out = (float*)d_out;

    char* ws = (char*)d_ws;
    float*    y    = (float*)ws;    ws += (size_t)NTOK * 256 * 4;   // fp32 residual stream
    ushort_t* big  = (ushort_t*)ws; ws += (size_t)NTOK * 1024 * 2;  // qkv (768) / h1 (1024) bf16
    ushort_t* xob  = (ushort_t*)ws; ws += (size_t)NTOK * 256 * 2;   // LN out / attn out bf16
    ushort_t* bt_qkv = (ushort_t*)ws; ws += (size_t)4 * 768 * 256 * 2;
    ushort_t* bt_out = (ushort_t*)ws; ws += (size_t)4 * 256 * 256 * 2;
    ushort_t* bt_fc1 = (ushort_t*)ws; ws += (size_t)4 * 1024 * 256 * 2;
    ushort_t* bt_fc2 = (ushort_t*)ws; ws += (size_t)4 * 256 * 1024 * 2;

    transpose_w<<<dim3((256 * 768 + 255) / 256, 4), 256, 0, stream>>>(qkv_w, bt_qkv, 256, 768);
    transpose_w<<<dim3((256 * 256 + 255) / 256, 4), 256, 0, stream>>>(out_w, bt_out, 256, 256);
    transpose_w<<<dim3((256 * 1024 + 255) / 256, 4), 256, 0, stream>>>(fc1_w, bt_fc1, 256, 1024);
    transpose_w<<<dim3((1024 * 256 + 255) / 256, 4), 256, 0, stream>>>(fc2_w, bt_fc2, 1024, 256);

    conv_kernel<<<NTOK, 256, 0, stream>>>(x, conv_w, conv_b, y);

    for (int i = 0; i < 4; ++i) {
        int sh = i & 1;
        ln_kernel<<<NTOK / 4, 256, 0, stream>>>(y, xob, ln1_s + i * 256, ln1_b + i * 256);
        gemm_bt<<<dim3(NTOK / 128, 6), 256, 0, stream>>>(
            xob, bt_qkv + (size_t)i * 768 * 256, NTOK, 768, 256, nullptr, 0, big, nullptr);
        attn_mfma<<<dim3(NWIN, 8, 2), 256, 0, stream>>>(
            big, xob, bias_tab + (size_t)i * NBIAS * 8, sh);
        gemm_bt<<<dim3(NTOK / 128, 2), 256, 0, stream>>>(
            xob, bt_out + (size_t)i * 256 * 256, NTOK, 256, 256, out_b + i * 256, 2, nullptr, y);
        ln_kernel<<<NTOK / 4, 256, 0, stream>>>(y, xob, ln2_s + i * 256, ln2_b + i * 256);
        gemm_bt<<<dim3(NTOK / 128, 8), 256, 0, stream>>>(
            xob, bt_fc1 + (size_t)i * 1024 * 256, NTOK, 1024, 256, fc1_b + i * 1024, 1, big, nullptr);
        gemm_bt<<<dim3(NTOK / 128, 2), 256, 0, stream>>>(
            big, bt_fc2 + (size_t)i * 256 * 1024, NTOK, 256, 1024, fc2_b + i * 256, 2, nullptr, y);
    }

    out_permute<<<dim3(NTOK / 64, 4), 256, 0, stream>>>(y, out);
}

// Round 4
// 1453.582 us; speedup vs baseline: 2.4911x; 1.2709x over previous
//
#include <hip/hip_runtime.h>

typedef unsigned short ushort_t;
typedef unsigned int   uint_t;

#define NTOK 50176          // B*D*Hp*Wp = 2*8*56*56
#define NWIN 98             // (8/4)*(56/8)*(56/8)
#define NBIAS 1575          // 7*15*15

typedef __attribute__((ext_vector_type(8))) short bf16x8;
typedef __attribute__((ext_vector_type(4))) float floatx4;

static __device__ __forceinline__ float lo2f(uint_t u) { return __uint_as_float(u << 16); }
static __device__ __forceinline__ float hi2f(uint_t u) { return __uint_as_float(u & 0xffff0000u); }
static __device__ __forceinline__ ushort_t f2b(float f) {
    union { float f; uint_t u; } v; v.f = f;
    uint_t u = v.u + 0x7fffu + ((v.u >> 16) & 1u);
    return (ushort_t)(u >> 16);
}

// ---------------- weight transpose + fp32->bf16 cast: dst[n*K+k] = bf16(src[k*N+n])
__global__ void transpose_w(const float* __restrict__ src, ushort_t* __restrict__ dst,
                            int K, int N) {
    long base = (long)blockIdx.y * K * N;
    int idx = blockIdx.x * 256 + threadIdx.x;
    if (idx < K * N) {
        int k = idx / N, n = idx - k * N;
        dst[base + (long)n * K + k] = f2b(src[base + idx]);
    }
}

// ---------------- elementwise fp32 -> bf16 cast
__global__ void cast_bf16(const float* __restrict__ src, ushort_t* __restrict__ dst, int n) {
    int i = blockIdx.x * 256 + threadIdx.x;
    if (i < n) dst[i] = f2b(src[i]);
}

// ---------------- im2row: A[tok, 64] bf16 patch matrix from X (NCDHW fp32)
// thread = (token, ic, kh): reads float4 at (b, ic, d, h*4+kh, w*4), writes 4 bf16
__global__ void im2row(const float* __restrict__ X, ushort_t* __restrict__ A) {
    int idx = blockIdx.x * 256 + threadIdx.x;   // NTOK*16 total
    int t = idx >> 4;
    int k = idx & 15;
    int ic = k >> 2, kh = k & 3;
    int w = t % 56, h = (t / 56) % 56, d = (t / 3136) % 8, b = t / 25088;
    long xi = (((long)(b * 4 + ic) * 8 + d) * 224 + (h * 4 + kh)) * 224 + w * 4;
    float4 u = *(const float4*)(X + xi);
    ushort_t* ap = A + (long)t * 64 + ic * 16 + kh * 4;
    ap[0] = f2b(u.x); ap[1] = f2b(u.y); ap[2] = f2b(u.z); ap[3] = f2b(u.w);
}

// ---------------- LayerNorm: 4 tokens per block, one wave per token; fp32 in, bf16 out
__global__ void ln_kernel(const float* __restrict__ Y, ushort_t* __restrict__ Xn,
                          const float* __restrict__ S, const float* __restrict__ Bb) {
    int wv = threadIdx.x >> 6, lane = threadIdx.x & 63;
    long t = (long)blockIdx.x * 4 + wv;
    const float* y = Y + t * 256;
    float v[4], s = 0.f, s2 = 0.f;
#pragma unroll
    for (int r = 0; r < 4; ++r) { v[r] = y[lane + 64 * r]; s += v[r]; s2 += v[r] * v[r]; }
#pragma unroll
    for (int off = 32; off; off >>= 1) { s += __shfl_xor(s, off, 64); s2 += __shfl_xor(s2, off, 64); }
    float mu = s * (1.f / 256.f);
    float var = s2 * (1.f / 256.f) - mu * mu;
    float rstd = rsqrtf(var + 1e-5f);
#pragma unroll
    for (int r = 0; r < 4; ++r) {
        int c = lane + 64 * r;
        Xn[t * 256 + c] = f2b((v[r] - mu) * rstd * S[c] + Bb[c]);
    }
}

// ---------------- GEMM: C[M,N] = A[M,K] @ B[K,N] via BT[N,K]; m97-style 128x128 tile
// mode 0: store bf16; mode 1: bias+gelu bf16; mode 2: Y += acc+bias (fp32); mode 3: Y = acc+bias (fp32)
__global__ __launch_bounds__(256, 2) void gemm_bt(
    const ushort_t* __restrict__ A, const ushort_t* __restrict__ BT,
    int M, int N, int K,
    const float* __restrict__ bias, int mode,
    ushort_t* __restrict__ C, float* __restrict__ Y) {
    __shared__ ushort_t As[128 * 32];
    __shared__ ushort_t Bs[128 * 32];
    const int tid = threadIdx.x;
    const int wv = tid >> 6;
    const int lane = tid & 63;
    const int quad = lane >> 4;
    const int l15 = lane & 15;
    const long m0 = (long)blockIdx.x * 128;
    const long n0 = (long)blockIdx.y * 128;
    const int wm = (wv & 1) * 64;
    const int wn = (wv >> 1) * 64;
    const int r_loc = lane >> 2;
    const int k_loc = (lane & 3) * 8;

    floatx4 acc[4][4] = {};

    const ushort_t* Ab = A + m0 * K;
    const ushort_t* Bb = BT + n0 * K;

    for (int kt = 0; kt < K; kt += 32) {
#pragma unroll
        for (int q = 0; q < 2; ++q) {
            int slot = wv * 2 + q;
            int row = slot * 16 + r_loc;
            __builtin_amdgcn_global_load_lds(
                (const __attribute__((address_space(1))) void*)(Ab + (long)row * K + kt + k_loc),
                (__attribute__((address_space(3))) void*)(As + slot * 512), 16, 0, 0);
            __builtin_amdgcn_global_load_lds(
                (const __attribute__((address_space(1))) void*)(Bb + (long)row * K + kt + k_loc),
                (__attribute__((address_space(3))) void*)(Bs + slot * 512), 16, 0, 0);
        }
        __syncthreads();
        bf16x8 af[4], bfr[4];
#pragma unroll
        for (int i = 0; i < 4; ++i) {
            af[i]  = *(const bf16x8*)(As + (wm + i * 16 + l15) * 32 + quad * 8);
            bfr[i] = *(const bf16x8*)(Bs + (wn + i * 16 + l15) * 32 + quad * 8);
        }
#pragma unroll
        for (int mi = 0; mi < 4; ++mi)
#pragma unroll
            for (int ni = 0; ni < 4; ++ni)
                acc[mi][ni] = __builtin_amdgcn_mfma_f32_16x16x32_bf16(af[mi], bfr[ni], acc[mi][ni], 0, 0, 0);
        __syncthreads();
    }

    if (mode == 2) {
#pragma unroll
        for (int mi = 0; mi < 4; ++mi)
#pragma unroll
            for (int ni = 0; ni < 4; ++ni) {
                long col = n0 + wn + ni * 16 + l15;
                float bv = bias[col];
#pragma unroll
                for (int r = 0; r < 4; ++r) {
                    long row = m0 + wm + mi * 16 + quad * 4 + r;
                    Y[row * N + col] += acc[mi][ni][r] + bv;
                }
            }
    } else if (mode == 3) {
#pragma unroll
        for (int mi = 0; mi < 4; ++mi)
#pragma unroll
            for (int ni = 0; ni < 4; ++ni) {
                long col = n0 + wn + ni * 16 + l15;
                float bv = bias[col];
#pragma unroll
                for (int r = 0; r < 4; ++r) {
                    long row = m0 + wm + mi * 16 + quad * 4 + r;
                    Y[row * N + col] = acc[mi][ni][r] + bv;
                }
            }
    } else {
#pragma unroll
        for (int mi = 0; mi < 4; ++mi)
#pragma unroll
            for (int ni = 0; ni < 4; ++ni) {
                long col = n0 + wn + ni * 16 + l15;
                float bv = bias ? bias[col] : 0.f;
#pragma unroll
                for (int r = 0; r < 4; ++r) {
                    long row = m0 + wm + mi * 16 + quad * 4 + r;
                    float v = acc[mi][ni][r] + bv;
                    if (mode == 1) {
                        float x3 = v * v * v;
                        v = 0.5f * v * (1.f + tanhf(0.7978845608028654f * (v + 0.044715f * x3)));
                    }
                    C[row * N + col] = f2b(v);
                }
            }
    }
}

// ---------------- MFMA window attention: block = (window, head, batch), 4 waves
#define PSTRIDE 260
#define VTSTRIDE 264
__global__ __launch_bounds__(256, 2) void attn_mfma(
    const ushort_t* __restrict__ QKV, ushort_t* __restrict__ O,
    const float* __restrict__ BiasTab, int shifted) {
    __shared__ ushort_t Ks[256 * 32];                 // K rows [tok][dim]
    __shared__ ushort_t Vt[32 * VTSTRIDE];            // V^T [dim][tok]
    __shared__ ushort_t Pl[4 * 16 * PSTRIDE];         // per-wave P tiles
    __shared__ float bias_s[NBIAS];
    __shared__ int tok_s[256];
    __shared__ int reg_s[256];

    const int tid = threadIdx.x;
    const int wv = tid >> 6;
    const int lane = tid & 63;
    const int quad = lane >> 4;
    const int l15 = lane & 15;
    const int wdx = blockIdx.x, hd = blockIdx.y, b = blockIdx.z;
    const int wd = wdx / 49;
    const int wh = (wdx / 7) % 7;
    const int ww = wdx % 7;

    {
        const int t = tid;
        const int di = t >> 6, hi = (t >> 3) & 7, wi = t & 7;
        const int d = wd * 4 + di, h = wh * 8 + hi, w = ww * 8 + wi;
        int d0 = d, h0 = h, w0 = w;
        if (shifted) { d0 = (d + 2) & 7; h0 = (h + 4) % 56; w0 = (w + 4) % 56; }
        const long tok = ((long)((b * 8 + d0) * 56 + h0)) * 56 + w0;
        tok_s[t] = (int)tok;
        if (shifted) {
            int rd = d < 4 ? 0 : (d < 6 ? 1 : 2);
            int rh = h < 48 ? 0 : (h < 52 ? 1 : 2);
            int rw = w < 48 ? 0 : (w < 52 ? 1 : 2);
            reg_s[t] = rd * 9 + rh * 3 + rw;
        } else reg_s[t] = 0;
        const uint4* kp = (const uint4*)(QKV + tok * 768 + 256 + hd * 32);
        const uint4* vp = (const uint4*)(QKV + tok * 768 + 512 + hd * 32);
        uint4* kd = (uint4*)(Ks + t * 32);
#pragma unroll
        for (int p = 0; p < 4; ++p) kd[p] = kp[p];
#pragma unroll
        for (int p = 0; p < 4; ++p) {
            uint4 vvu = vp[p];
            uint_t uu[4] = {vvu.x, vvu.y, vvu.z, vvu.w};
#pragma unroll
            for (int e = 0; e < 4; ++e) {
                int dd = p * 8 + e * 2;
                Vt[dd * VTSTRIDE + t]       = (ushort_t)(uu[e] & 0xffffu);
                Vt[(dd + 1) * VTSTRIDE + t] = (ushort_t)(uu[e] >> 16);
            }
        }
        for (int r = t; r < NBIAS; r += 256) bias_s[r] = BiasTab[r * 8 + hd];
    }
    __syncthreads();

    const float scale = 0.17677669529663687f;
    ushort_t* Pw = Pl + wv * 16 * PSTRIDE;

    for (int rg = 0; rg < 4; ++rg) {
        const int rti = wv * 4 + rg;
        bf16x8 aq;
        {
            int tq = tok_s[rti * 16 + l15];
            const uint4* qp = (const uint4*)(QKV + (long)tq * 768 + hd * 32 + quad * 8);
            union { uint4 u; bf16x8 v; } cv; cv.u = *qp; aq = cv.v;
        }
        int idv[4], ihv[4], iwv4[4], rq[4];
#pragma unroll
        for (int r = 0; r < 4; ++r) {
            int i = rti * 16 + quad * 4 + r;
            idv[r] = i >> 6; ihv[r] = (i >> 3) & 7; iwv4[r] = i & 7;
            rq[r] = reg_s[i];
        }
        floatx4 Sc[16];
#pragma unroll
        for (int nt = 0; nt < 16; ++nt) {
            bf16x8 bk = *(const bf16x8*)(Ks + (nt * 16 + l15) * 32 + quad * 8);
            floatx4 z = {};
            Sc[nt] = __builtin_amdgcn_mfma_f32_16x16x32_bf16(aq, bk, z, 0, 0, 0);
        }
        float m4[4] = {-3e38f, -3e38f, -3e38f, -3e38f};
#pragma unroll
        for (int nt = 0; nt < 16; ++nt) {
            int j = nt * 16 + l15;
            int jd = j >> 6, jh = (j >> 3) & 7, jw = j & 7;
            int rk = reg_s[j];
#pragma unroll
            for (int r = 0; r < 4; ++r) {
                float s = Sc[nt][r] * scale +
                          bias_s[(idv[r] - jd + 3) * 225 + (ihv[r] - jh + 7) * 15 + (iwv4[r] - jw + 7)];
                if (shifted && (rq[r] != rk)) s = -1e9f;
                Sc[nt][r] = s;
                m4[r] = fmaxf(m4[r], s);
            }
        }
#pragma unroll
        for (int r = 0; r < 4; ++r) {
            m4[r] = fmaxf(m4[r], __shfl_xor(m4[r], 1));
            m4[r] = fmaxf(m4[r], __shfl_xor(m4[r], 2));
            m4[r] = fmaxf(m4[r], __shfl_xor(m4[r], 4));
            m4[r] = fmaxf(m4[r], __shfl_xor(m4[r], 8));
        }
        float l4[4] = {0.f, 0.f, 0.f, 0.f};
#pragma unroll
        for (int nt = 0; nt < 16; ++nt)
#pragma unroll
            for (int r = 0; r < 4; ++r) {
                float p = __expf(Sc[nt][r] - m4[r]);
                l4[r] += p;
                Sc[nt][r] = p;
            }
#pragma unroll
        for (int r = 0; r < 4; ++r) {
            l4[r] += __shfl_xor(l4[r], 1);
            l4[r] += __shfl_xor(l4[r], 2);
            l4[r] += __shfl_xor(l4[r], 4);
            l4[r] += __shfl_xor(l4[r], 8);
        }
#pragma unroll
        for (int nt = 0; nt < 16; ++nt)
#pragma unroll
            for (int r = 0; r < 4; ++r)
                Pw[(quad * 4 + r) * PSTRIDE + nt * 16 + l15] = f2b(Sc[nt][r]);
        __builtin_amdgcn_s_waitcnt(0xC07F);       // lgkmcnt(0)
        __builtin_amdgcn_wave_barrier();
        float inv4[4];
#pragma unroll
        for (int r = 0; r < 4; ++r) inv4[r] = 1.f / l4[r];
#pragma unroll
        for (int ct = 0; ct < 2; ++ct) {
            floatx4 oa = {};
#pragma unroll
            for (int kt = 0; kt < 8; ++kt) {
                bf16x8 ap = *(const bf16x8*)(Pw + l15 * PSTRIDE + kt * 32 + quad * 8);
                bf16x8 bv = *(const bf16x8*)(Vt + (ct * 16 + l15) * VTSTRIDE + kt * 32 + quad * 8);
                oa = __builtin_amdgcn_mfma_f32_16x16x32_bf16(ap, bv, oa, 0, 0, 0);
            }
#pragma unroll
            for (int r = 0; r < 4; ++r) {
                int i = rti * 16 + quad * 4 + r;
                long tq = tok_s[i];
                O[tq * 256 + hd * 32 + ct * 16 + l15] = f2b(oa[r] * inv4[r]);
            }
        }
        __builtin_amdgcn_s_waitcnt(0xC07F);
        __builtin_amdgcn_wave_barrier();
    }
}

// ---------------- final permute: y (tok, C) fp32 -> out (B, C, D, Hp, Wp) fp32
__global__ void out_permute(const float* __restrict__ Y, float* __restrict__ Out) {
    __shared__ float tile[64][65];
    const int t0 = blockIdx.x * 64;
    const int c0 = blockIdx.y * 64;
    const int tid = threadIdx.x;
    const int a = tid >> 6;
    const int bx = tid & 63;
#pragma unroll
    for (int s8 = 0; s8 < 16; ++s8) {
        int tt = a + s8 * 4;
        tile[tt][bx] = Y[(long)(t0 + tt) * 256 + c0 + bx];
    }
    __syncthreads();
#pragma unroll
    for (int s8 = 0; s8 < 16; ++s8) {
        int cc = a + s8 * 4;
        int tok = t0 + bx;
        int bb = tok / 25088;
        int rem = tok - bb * 25088;
        Out[((long)(bb * 256 + c0 + cc)) * 25088 + rem] = tile[bx][cc];
    }
}

extern "C" void kernel_launch(void* const* d_in, const int* in_sizes, int n_in,
                              void* d_out, int out_size, void* d_ws, size_t ws_size,
                              hipStream_t stream) {
    (void)in_sizes; (void)n_in; (void)out_size; (void)ws_size;
    const float* x        = (const float*)d_in[0];
    const float* conv_w   = (const float*)d_in[1];
    const float* conv_b   = (const float*)d_in[2];
    const float* ln1_s    = (const float*)d_in[3];
    const float* ln1_b    = (const float*)d_in[4];
    const float* qkv_w    = (const float*)d_in[5];
    const float* out_w    = (const float*)d_in[6];
    const float* out_b    = (const float*)d_in[7];
    const float* bias_tab = (const float*)d_in[8];
    const float* ln2_s    = (const float*)d_in[9];
    const float* ln2_b    = (const float*)d_in[10];
    const float* fc1_w    = (const float*)d_in[11];
    const float* fc1_b    = (const float*)d_in[12];
    const float* fc2_w    = (const float*)d_in[13];
    const float* fc2_b    = (const float*)d_in[14];
    float* out = (float*)d_out;

    char* ws = (char*)d_ws;
    float*    y    = (float*)ws;    ws += (size_t)NTOK * 256 * 4;   // fp32 residual stream
    ushort_t* big  = (ushort_t*)ws; ws += (size_t)NTOK * 1024 * 2;  // qkv/h1/im2row bf16
    ushort_t* xob  = (ushort_t*)ws; ws += (size_t)NTOK * 256 * 2;   // LN out / attn out bf16
    ushort_t* bt_qkv = (ushort_t*)ws; ws += (size_t)4 * 768 * 256 * 2;
    ushort_t* bt_out = (ushort_t*)ws; ws += (size_t)4 * 256 * 256 * 2;
    ushort_t* bt_fc1 = (ushort_t*)ws; ws += (size_t)4 * 1024 * 256 * 2;
    ushort_t* bt_fc2 = (ushort_t*)ws; ws += (size_t)4 * 256 * 1024 * 2;
    ushort_t* cw_bf  = (ushort_t*)ws; ws += (size_t)256 * 64 * 2;

    transpose_w<<<dim3((256 * 768 + 255) / 256, 4), 256, 0, stream>>>(qkv_w, bt_qkv, 256, 768);
    transpose_w<<<dim3((256 * 256 + 255) / 256, 4), 256, 0, stream>>>(out_w, bt_out, 256, 256);
    transpose_w<<<dim3((256 * 1024 + 255) / 256, 4), 256, 0, stream>>>(fc1_w, bt_fc1, 256, 1024);
    transpose_w<<<dim3((1024 * 256 + 255) / 256, 4), 256, 0, stream>>>(fc2_w, bt_fc2, 1024, 256);

    // conv as GEMM: conv_w (O,I,1,4,4) is already BT[256][64] row-major — cast only
    cast_bf16<<<(256 * 64 + 255) / 256, 256, 0, stream>>>(conv_w, cw_bf, 256 * 64);
    im2row<<<NTOK * 16 / 256, 256, 0, stream>>>(x, big);
    gemm_bt<<<dim3(NTOK / 128, 2), 256, 0, stream>>>(
        big, cw_bf, NTOK, 256, 64, conv_b, 3, nullptr, y);

    for (int i = 0; i < 4; ++i) {
        int sh = i & 1;
        ln_kernel<<<NTOK / 4, 256, 0, stream>>>(y, xob, ln1_s + i * 256, ln1_b + i * 256);
        gemm_bt<<<dim3(NTOK / 128, 6), 256, 0, stream>>>(
            xob, bt_qkv + (size_t)i * 768 * 256, NTOK, 768, 256, nullptr, 0, big, nullptr);
        attn_mfma<<<dim3(NWIN, 8, 2), 256, 0, stream>>>(
            big, xob, bias_tab + (size_t)i * NBIAS * 8, sh);
        gemm_bt<<<dim3(NTOK / 128, 2), 256, 0, stream>>>(
            xob, bt_out + (size_t)i * 256 * 256, NTOK, 256, 256, out_b + i * 256, 2, nullptr, y);
        ln_kernel<<<NTOK / 4, 256, 0, stream>>>(y, xob, ln2_s + i * 256, ln2_b + i * 256);
        gemm_bt<<<dim3(NTOK / 128, 8), 256, 0, stream>>>(
            xob, bt_fc1 + (size_t)i * 1024 * 256, NTOK, 1024, 256, fc1_b + i * 1024, 1, big, nullptr);
        gemm_bt<<<dim3(NTOK / 128, 2), 256, 0, stream>>>(
            big, bt_fc2 + (size_t)i * 256 * 1024, NTOK, 256, 1024, fc2_b + i * 256, 2, nullptr, y);
    }

    out_permute<<<dim3(NTOK / 64, 4), 256, 0, stream>>>(y, out);
}